// Round 7
// baseline (54940.875 us; speedup 1.0000x reference)
//
#include <hip/hip_runtime.h>
#include <stdint.h>

#define SEQ 8192
#define EMB 1024
#define HID 2048
#define NCH 256

#define SCAN_B 64                   // persistent blocks (co-resident, proven R1-R6)
#define SCAN_T 512                  // 8 waves/block
#define ROWS_PB (HID / SCAN_B)      // 32 rows per block (4 per wave)
#define SENT 0xFFFFFFFFu            // poison: tanh never produces this pattern
#define NREP 8                      // one ring replica PER WAVE-INDEX (fan-in /2)
#define NSLOT 8                     // ring slots (skew<=1 proven; margin 4)

typedef unsigned long long u64;

// ---------------------------------------------------------------------------
// Generic fp32 "TN" GEMM: C[m][n] = bias[n] + dot(X[m][:], W[n][:])
// ---------------------------------------------------------------------------
__global__ __launch_bounds__(256) void gemm_tn(const float* __restrict__ X,
                                               const float* __restrict__ W,
                                               const float* __restrict__ bias,
                                               float* __restrict__ C,
                                               int M, int N, int K)
{
    __shared__ float Xs[16][68];
    __shared__ float Ws[16][68];
    const int m0 = blockIdx.x * 64, n0 = blockIdx.y * 64;
    const int tid  = threadIdx.x;
    const int lrow = tid >> 2;
    const int kq   = (tid & 3) * 4;
    const int tx   = tid & 15, ty = tid >> 4;
    float acc[4][4] = {};
    const float* Xp = X + (size_t)(m0 + lrow) * K + kq;
    const float* Wp = W + (size_t)(n0 + lrow) * K + kq;

    for (int k0 = 0; k0 < K; k0 += 16) {
        float4 xv = *(const float4*)(Xp + k0);
        float4 wv = *(const float4*)(Wp + k0);
        __syncthreads();
        Xs[kq+0][lrow] = xv.x; Xs[kq+1][lrow] = xv.y;
        Xs[kq+2][lrow] = xv.z; Xs[kq+3][lrow] = xv.w;
        Ws[kq+0][lrow] = wv.x; Ws[kq+1][lrow] = wv.y;
        Ws[kq+2][lrow] = wv.z; Ws[kq+3][lrow] = wv.w;
        __syncthreads();
#pragma unroll
        for (int kk = 0; kk < 16; ++kk) {
            float4 av = *(const float4*)&Xs[kk][ty * 4];
            float4 bv = *(const float4*)&Ws[kk][tx * 4];
            float a[4] = {av.x, av.y, av.z, av.w};
            float b[4] = {bv.x, bv.y, bv.z, bv.w};
#pragma unroll
            for (int i = 0; i < 4; ++i)
#pragma unroll
                for (int j = 0; j < 4; ++j)
                    acc[i][j] += a[i] * b[j];
        }
    }
#pragma unroll
    for (int i = 0; i < 4; ++i) {
        const int m = m0 + ty * 4 + i;
#pragma unroll
        for (int j = 0; j < 4; ++j) {
            const int n = n0 + tx * 4 + j;
            C[(size_t)m * N + n] = acc[i][j] + bias[n];
        }
    }
}

// tanh(x) = 1 - 2/(exp2(2x*log2e)+1); ~1e-6 rel error, finite everywhere.
__device__ __forceinline__ float fast_tanh(float x)
{
    float e = __builtin_amdgcn_exp2f(x * 2.885390081777927f);
    return 1.0f - 2.0f * __builtin_amdgcn_rcpf(e + 1.0f);
}

__device__ __forceinline__ u64 ld_agent(const u64* p)
{
    return __hip_atomic_load(p, __ATOMIC_RELAXED, __HIP_MEMORY_SCOPE_AGENT);
}

__device__ __forceinline__ int is_poison(u64 x0, u64 x1)
{
    return ((unsigned)x0 == SENT) | ((unsigned)(x0 >> 32) == SENT) |
           ((unsigned)x1 == SENT) | ((unsigned)(x1 >> 32) == SENT);
}

// ---------------------------------------------------------------------------
// Persistent RNN scan, R13: DIRECT RING->REGISTER GATHER (no LDS relay).
//
// Six protocol variants (R6..R12) all shared one structure: wave stages a
// chunk to LDS, fences, flags; consumers spin, then ds_read.  That relay
// (LDS write + lgkmcnt + flag + spin + ds_read ~= 300-400 cy) sits on the
// gating path of EVERY step, and adds a second max() layer (slowest staging
// wave) on top of the arrival max.  R12 additionally proved same-address
// multi-outstanding polls coalesce in the MSHR (useless), so the poll
// sampling period is pinned at ~RTT; the only removable latency left on the
// consumer side is the relay itself.
//
// Key fact: each wave's FMA input pattern h[4*lane + 256*j] is already
// lane-contiguous for fixed j -> a wave can read its ENTIRE input directly
// from the ring slot as 8 coalesced chunk-loads (2 x u64 agent loads per
// chunk, poison-checked), processed strictly j=0..7 (bit-identical FP
// order).  Chunks are INDEPENDENT addresses -> the 16 initial loads
// pipeline; chunk j+1's flight overlaps chunk j's FMA; retries hit only
// not-yet-arrived chunks.  No LDS, no flags, no fences, no barrier, no
// intra-block coupling of any kind.
//
// Cost: every wave reads the full 8 KB slot (8x poll reads, all L3-resident
// -- invisible to HBM).  Mitigation: NREP 4->8, replica = wave-index, so
// per-line reader fan-in halves vs R9 (64 blocks x 1 wave per replica).
// Producer: 8 signal + 8 poison + 1 H = 17 stores (issue ~70 cy, acks
// overlap the tail as proven in R9; consumers' counted waits never touch
// another wave's acks).
//
// Protocol invariants unchanged: store IS the signal (word-granular
// poison); a wave passes step t only after all 2048 words of slot t&7 are
// non-poison => global skew <= 1; poison written at distance 5, slot reuse
// at distance 8.  Slot 0 pre-zeroed (h0), all else pre-poisoned.
// ---------------------------------------------------------------------------
__global__ __launch_bounds__(SCAN_T, 2) void rnn_scan(
    const int*  __restrict__ seq,
    const float* __restrict__ waa,
    const float* __restrict__ P,
    float* __restrict__ H,                 // (SEQ+1) x HID; plain (not polled)
    unsigned* __restrict__ ring)           // NREP x NSLOT x HID
{
    const int b    = blockIdx.x;
    const int tid  = threadIdx.x;
    const int wv   = tid >> 6;        // wave id 0..7
    const int lane = tid & 63;
    const int R0   = b * ROWS_PB + wv * 4;   // first of this wave's 4 rows

    // One-time weight load: w[i][4j+e] = waa[R0+i][256j+4*lane+e].
    float w0[32], w1[32], w2[32], w3[32];
#pragma unroll
    for (int j = 0; j < 8; ++j) {
        const float* base = waa + 256 * j + 4 * lane;
        float4 a = *(const float4*)(base + (size_t)(R0 + 0) * HID);
        float4 c = *(const float4*)(base + (size_t)(R0 + 1) * HID);
        float4 d = *(const float4*)(base + (size_t)(R0 + 2) * HID);
        float4 e = *(const float4*)(base + (size_t)(R0 + 3) * HID);
        w0[4*j+0]=a.x; w0[4*j+1]=a.y; w0[4*j+2]=a.z; w0[4*j+3]=a.w;
        w1[4*j+0]=c.x; w1[4*j+1]=c.y; w1[4*j+2]=c.z; w1[4*j+3]=c.w;
        w2[4*j+0]=d.x; w2[4*j+1]=d.y; w2[4*j+2]=d.z; w2[4*j+3]=d.w;
        w3[4*j+0]=e.x; w3[4*j+1]=e.y; w3[4*j+2]=e.z; w3[4*j+3]=e.w;
    }
#pragma unroll
    for (int k = 0; k < 32; ++k) {
        asm volatile("" : "+v"(w0[k])); asm volatile("" : "+v"(w1[k]));
        asm volatile("" : "+v"(w2[k])); asm volatile("" : "+v"(w3[k]));
    }

    // This wave's private replica (one replica per wave-index).
    unsigned* myring = ring + (size_t)wv * NSLOT * HID;

#pragma unroll 1
    for (int t = 0; t < SEQ; ++t) {
        // xa for this step (read-only, cached) -- overlaps the gather.
        const int ch = seq[t];
        float xav = 0.f;
        if (lane < 4) xav = P[(size_t)ch * HID + R0 + lane];

        // Per-lane base: chunk j occupies u64s [128j + 2*lane, +1].
        const u64* p8 = (const u64*)
            (myring + (size_t)(t & (NSLOT - 1)) * HID) + 2 * lane;

        // Issue all 16 gather loads (8 independent chunks) up front.
        u64 lo[8], hi[8];
#pragma unroll
        for (int j = 0; j < 8; ++j) {
            lo[j] = ld_agent(p8 + 128 * j);
            hi[j] = ld_agent(p8 + 128 * j + 1);
        }

        // In-order chunk processing (bit-identical accumulation order);
        // arrival of later chunks overlaps FMA of earlier ones.
        float a0 = 0.f, a1 = 0.f, a2 = 0.f, a3 = 0.f;
#pragma unroll
        for (int j = 0; j < 8; ++j) {
            u64 x0 = lo[j], x1 = hi[j];
            while (is_poison(x0, x1)) {
                x0 = ld_agent(p8 + 128 * j);
                x1 = ld_agent(p8 + 128 * j + 1);
            }
            const float h0 = __uint_as_float((unsigned)(x0));
            const float h1 = __uint_as_float((unsigned)(x0 >> 32));
            const float h2 = __uint_as_float((unsigned)(x1));
            const float h3 = __uint_as_float((unsigned)(x1 >> 32));
            a0 += w0[4*j+0]*h0 + w0[4*j+1]*h1 + w0[4*j+2]*h2 + w0[4*j+3]*h3;
            a1 += w1[4*j+0]*h0 + w1[4*j+1]*h1 + w1[4*j+2]*h2 + w1[4*j+3]*h3;
            a2 += w2[4*j+0]*h0 + w2[4*j+1]*h1 + w2[4*j+2]*h2 + w2[4*j+3]*h3;
            a3 += w3[4*j+0]*h0 + w3[4*j+1]*h1 + w3[4*j+2]*h2 + w3[4*j+3]*h3;
        }

        // Paired butterfly: row (lane&3)'s full sum ends in lane l.
        a0 += __shfl_xor(a0, 1, 64);
        a1 += __shfl_xor(a1, 1, 64);
        a2 += __shfl_xor(a2, 1, 64);
        a3 += __shfl_xor(a3, 1, 64);
        float m01 = (lane & 1) ? a1 : a0;
        float m23 = (lane & 1) ? a3 : a2;
        m01 += __shfl_xor(m01, 2, 64);
        m23 += __shfl_xor(m23, 2, 64);
        float m = (lane & 2) ? m23 : m01;
        m += __shfl_xor(m, 4, 64);
        m += __shfl_xor(m, 8, 64);
        m += __shfl_xor(m, 16, 64);
        m += __shfl_xor(m, 32, 64);

        if (lane < 4) {
            float hn = fast_tanh(xav + m);
            const unsigned hu = __float_as_uint(hn);
            const int row = R0 + lane;
            const int s1 = (t + 1) & (NSLOT - 1);
            const int s5 = (t + 5) & (NSLOT - 1);
            // signals to ALL replicas first (consumer-critical), ...
#pragma unroll
            for (int r = 0; r < NREP; ++r)
                __hip_atomic_store(ring + ((size_t)r * NSLOT + s1) * HID + row,
                                   hu, __ATOMIC_RELAXED,
                                   __HIP_MEMORY_SCOPE_AGENT);
            // ... then poisons (needed 4 steps out), then plain H row.
#pragma unroll
            for (int r = 0; r < NREP; ++r)
                __hip_atomic_store(ring + ((size_t)r * NSLOT + s5) * HID + row,
                                   SENT, __ATOMIC_RELAXED,
                                   __HIP_MEMORY_SCOPE_AGENT);
            H[(size_t)(t + 1) * HID + row] = hn;   // epilogue GEMM input
        }
        // store IS the signal; unique addresses per slot -> race-free
    }
}

__global__ void copy_h(const float* __restrict__ src, float* __restrict__ dst)
{
    int i = blockIdx.x * blockDim.x + threadIdx.x;
    if (i < HID) dst[i] = src[i];
}

// ---------------------------------------------------------------------------
extern "C" void kernel_launch(void* const* d_in, const int* in_sizes, int n_in,
                              void* d_out, int out_size, void* d_ws, size_t ws_size,
                              hipStream_t stream)
{
    const int*   seq  = (const int*)  d_in[0];
    const float* emb  = (const float*)d_in[1];
    const float* wax  = (const float*)d_in[2];
    const float* waxb = (const float*)d_in[3];
    const float* waa  = (const float*)d_in[4];
    const float* wya  = (const float*)d_in[5];
    const float* wyab = (const float*)d_in[6];
    float* out = (float*)d_out;

    // ws layout: H[(SEQ+1)][HID] fp32 | P[NCH][HID] fp32 | ring[8][8][HID] u32
    float*    H    = (float*)d_ws;
    float*    P    = (float*)((char*)d_ws + (size_t)(SEQ + 1) * HID * sizeof(float));
    unsigned* ring = (unsigned*)(P + (size_t)NCH * HID);

    // Re-init every call: ring all-poison, then slot 0 of each replica = h0 = 0.
    (void)hipMemsetAsync(ring, 0xFF, (size_t)NREP * NSLOT * HID * sizeof(unsigned), stream);
    for (int r = 0; r < NREP; ++r)
        (void)hipMemsetAsync(ring + (size_t)r * NSLOT * HID, 0,
                             HID * sizeof(unsigned), stream);

    // P = emb @ wax^T + wax_b   (M=256, N=2048, K=1024)
    dim3 gA(NCH / 64, HID / 64);
    gemm_tn<<<gA, 256, 0, stream>>>(emb, wax, waxb, P, NCH, HID, EMB);

    // Sequential recurrence (persistent, direct-gather + ring poison sync).
    rnn_scan<<<SCAN_B, SCAN_T, 0, stream>>>(seq, waa, P, H, ring);

    // out = H[1..SEQ] @ wya^T + wya_b   (M=8192, N=256, K=2048)
    dim3 gC(SEQ / 64, NCH / 64);
    gemm_tn<<<gC, 256, 0, stream>>>(H + HID, wya, wyab, out, SEQ, NCH, HID);

    // h_final = H[SEQ] -> tail of d_out
    copy_h<<<(HID + 255) / 256, 256, 0, stream>>>(H + (size_t)SEQ * HID,
                                                  out + (size_t)SEQ * NCH);
}

// Round 8
// 16590.448 us; speedup vs baseline: 3.3116x; 3.3116x over previous
//
#include <hip/hip_runtime.h>
#include <stdint.h>

#define SEQ 8192
#define EMB 1024
#define HID 2048
#define NCH 256

#define SCAN_B 64                   // persistent blocks (co-resident, proven R1-R6)
#define SCAN_T 512                  // 8 waves/block
#define ROWS_PB (HID / SCAN_B)      // 32 rows per block (4 per wave)
#define SENT 0xFFFFFFFFu            // poison: tanh never produces this pattern
#define NREP 4                      // ring replicas (spread L3 line ownership)
#define NSLOT 8                     // ring slots (skew<=1 proven; margin 4)

typedef unsigned uint4v __attribute__((ext_vector_type(4)));
typedef unsigned long long u64;

// ---------------------------------------------------------------------------
// Generic fp32 "TN" GEMM: C[m][n] = bias[n] + dot(X[m][:], W[n][:])
// ---------------------------------------------------------------------------
__global__ __launch_bounds__(256) void gemm_tn(const float* __restrict__ X,
                                               const float* __restrict__ W,
                                               const float* __restrict__ bias,
                                               float* __restrict__ C,
                                               int M, int N, int K)
{
    __shared__ float Xs[16][68];
    __shared__ float Ws[16][68];
    const int m0 = blockIdx.x * 64, n0 = blockIdx.y * 64;
    const int tid  = threadIdx.x;
    const int lrow = tid >> 2;
    const int kq   = (tid & 3) * 4;
    const int tx   = tid & 15, ty = tid >> 4;
    float acc[4][4] = {};
    const float* Xp = X + (size_t)(m0 + lrow) * K + kq;
    const float* Wp = W + (size_t)(n0 + lrow) * K + kq;

    for (int k0 = 0; k0 < K; k0 += 16) {
        float4 xv = *(const float4*)(Xp + k0);
        float4 wv = *(const float4*)(Wp + k0);
        __syncthreads();
        Xs[kq+0][lrow] = xv.x; Xs[kq+1][lrow] = xv.y;
        Xs[kq+2][lrow] = xv.z; Xs[kq+3][lrow] = xv.w;
        Ws[kq+0][lrow] = wv.x; Ws[kq+1][lrow] = wv.y;
        Ws[kq+2][lrow] = wv.z; Ws[kq+3][lrow] = wv.w;
        __syncthreads();
#pragma unroll
        for (int kk = 0; kk < 16; ++kk) {
            float4 av = *(const float4*)&Xs[kk][ty * 4];
            float4 bv = *(const float4*)&Ws[kk][tx * 4];
            float a[4] = {av.x, av.y, av.z, av.w};
            float b[4] = {bv.x, bv.y, bv.z, bv.w};
#pragma unroll
            for (int i = 0; i < 4; ++i)
#pragma unroll
                for (int j = 0; j < 4; ++j)
                    acc[i][j] += a[i] * b[j];
        }
    }
#pragma unroll
    for (int i = 0; i < 4; ++i) {
        const int m = m0 + ty * 4 + i;
#pragma unroll
        for (int j = 0; j < 4; ++j) {
            const int n = n0 + tx * 4 + j;
            C[(size_t)m * N + n] = acc[i][j] + bias[n];
        }
    }
}

// tanh(x) = 1 - 2/(exp2(2x*log2e)+1); ~1e-6 rel error, finite everywhere.
__device__ __forceinline__ float fast_tanh(float x)
{
    float e = __builtin_amdgcn_exp2f(x * 2.885390081777927f);
    return 1.0f - 2.0f * __builtin_amdgcn_rcpf(e + 1.0f);
}

__device__ __forceinline__ u64 ld_agent(const u64* p)
{
    return __hip_atomic_load(p, __ATOMIC_RELAXED, __HIP_MEMORY_SCOPE_AGENT);
}

__device__ __forceinline__ int is_poison(u64 x0, u64 x1)
{
    return ((unsigned)x0 == SENT) | ((unsigned)(x0 >> 32) == SENT) |
           ((unsigned)x1 == SENT) | ((unsigned)(x1 >> 32) == SENT);
}

// ---------------------------------------------------------------------------
// Persistent RNN scan, R14 = R9 (flag-dataflow relay; the relay is an 8x
// poll-traffic amortizer -- R13's direct gather proved that by exploding
// FETCH_SIZE to 5 GB) + ONE change: an ISSUE-ORDER-CORRECT early sample of
// slot t+1.
//
//   R10 already tried prefetching slot t+1 but issued the loads AFTER the
//   17 producer stores; vmcnt retires strictly in issue order, so waiting
//   for that prefetch meant draining all cross-XCD store-acks -> massive
//   regression.  Here the sample is issued at FMA-END, BEFORE the
//   butterfly/tanh/stores: in the wave's vmem queue it precedes the
//   stores, so the compiler's counted wait at the next loop top retires it
//   WITHOUT touching store acks.  Its ~RTT flight overlaps the ~400 cy
//   tail.  For the step-gating (late) block, remote h(t+1) rows are
//   already home by then -> valid sample, first poll round skipped
//   entirely (one full RTT off the serial chain).
//
//   Safety: slot (t+1)&7 was re-poisoned by every block 4 steps (~7 us)
//   earlier (same visibility margin the R6-proven poll relies on), and
//   same-address poison->signal stores from one producer thread are
//   coherence-ordered, so the sample reads poison or the final value --
//   never stale h.  Any poison -> fall into the unchanged R9 poll loop.
//   FP math and accumulation order bit-identical to R6/R9.
// ---------------------------------------------------------------------------
__global__ __launch_bounds__(SCAN_T, 2) void rnn_scan(
    const int*  __restrict__ seq,
    const float* __restrict__ waa,
    const float* __restrict__ P,
    float* __restrict__ H,                 // (SEQ+1) x HID; plain (not polled)
    unsigned* __restrict__ ring)           // NREP x NSLOT x HID
{
    const int b    = blockIdx.x;
    const int tid  = threadIdx.x;
    const int wv   = tid >> 6;        // wave id 0..7
    const int lane = tid & 63;
    const int R0   = b * ROWS_PB + wv * 4;   // first of this wave's 4 rows
    const int rep  = b & (NREP - 1);

    __shared__ float hbuf[2][HID];    // 16 KB parity double-buffer
    __shared__ int   flg[2][8];       // per-parity, per-chunk "staged@step"

    // One-time weight load: w[i][4j+e] = waa[R0+i][256j+4*lane+e].
    float w0[32], w1[32], w2[32], w3[32];
#pragma unroll
    for (int j = 0; j < 8; ++j) {
        const float* base = waa + 256 * j + 4 * lane;
        float4 a = *(const float4*)(base + (size_t)(R0 + 0) * HID);
        float4 c = *(const float4*)(base + (size_t)(R0 + 1) * HID);
        float4 d = *(const float4*)(base + (size_t)(R0 + 2) * HID);
        float4 e = *(const float4*)(base + (size_t)(R0 + 3) * HID);
        w0[4*j+0]=a.x; w0[4*j+1]=a.y; w0[4*j+2]=a.z; w0[4*j+3]=a.w;
        w1[4*j+0]=c.x; w1[4*j+1]=c.y; w1[4*j+2]=c.z; w1[4*j+3]=c.w;
        w2[4*j+0]=d.x; w2[4*j+1]=d.y; w2[4*j+2]=d.z; w2[4*j+3]=d.w;
        w3[4*j+0]=e.x; w3[4*j+1]=e.y; w3[4*j+2]=e.z; w3[4*j+3]=e.w;
    }
#pragma unroll
    for (int k = 0; k < 32; ++k) {
        asm volatile("" : "+v"(w0[k])); asm volatile("" : "+v"(w1[k]));
        asm volatile("" : "+v"(w2[k])); asm volatile("" : "+v"(w3[k]));
    }

    if (tid < 16) ((int*)flg)[tid] = -1;
    __syncthreads();                  // the ONLY barrier (flag init)

    unsigned* myring = ring + (size_t)rep * NSLOT * HID;

    // Loop-carried early sample; poison-init -> step 0 takes the poll path
    // (slot 0 is pre-zeroed h0, so that poll returns immediately).
    u64 e0 = ~0ull, e1 = ~0ull;

#pragma unroll 1
    for (int t = 0; t < SEQ; ++t) {
        // xa for this step (read-only, cached) -- overlaps the poll.
        const int ch = seq[t];
        float xav = 0.f;
        if (lane < 4) xav = P[(size_t)ch * HID + R0 + lane];

        // --- acquire my 4 words of slot t&7: early sample, else poll ---
        uint4v v;
        if (!is_poison(e0, e1)) {
            v.x = (unsigned)e0; v.y = (unsigned)(e0 >> 32);
            v.z = (unsigned)e1; v.w = (unsigned)(e1 >> 32);
        } else {
            const unsigned* pp =
                myring + (size_t)(t & (NSLOT - 1)) * HID + tid * 4;
            do {
                asm volatile("global_load_dwordx4 %0, %1, off sc0 sc1\n\t"
                             "s_waitcnt vmcnt(0)"
                             : "=v"(v) : "v"(pp) : "memory");
            } while (v.x == SENT || v.y == SENT ||
                     v.z == SENT || v.w == SENT);
        }
        *(uint4v*)&hbuf[t & 1][tid * 4] = v;   // 16B stride: conflict-free

        // publish chunk wv for parity t&1 (data-before-flag via lgkmcnt(0))
        asm volatile("s_waitcnt lgkmcnt(0)" ::: "memory");
        if (lane == 0) *(volatile int*)&flg[t & 1][wv] = t;

        // --- per-chunk gated compute: 8x {spin flag; b128 read; 16 FMA} ---
        float a0 = 0.f, a1 = 0.f, a2 = 0.f, a3 = 0.f;
        const float* hb = &hbuf[t & 1][4 * lane];
#pragma unroll
        for (int j = 0; j < 8; ++j) {
            while (*(volatile int*)&flg[t & 1][j] != t) { }
            asm volatile("" ::: "memory");   // no hbuf-read hoist above spin
            float4 hv = *(const float4*)(hb + 256 * j);
            a0 += w0[4*j+0]*hv.x + w0[4*j+1]*hv.y + w0[4*j+2]*hv.z + w0[4*j+3]*hv.w;
            a1 += w1[4*j+0]*hv.x + w1[4*j+1]*hv.y + w1[4*j+2]*hv.z + w1[4*j+3]*hv.w;
            a2 += w2[4*j+0]*hv.x + w2[4*j+1]*hv.y + w2[4*j+2]*hv.z + w2[4*j+3]*hv.w;
            a3 += w3[4*j+0]*hv.x + w3[4*j+1]*hv.y + w3[4*j+2]*hv.z + w3[4*j+3]*hv.w;
        }

        // --- EARLY SAMPLE of slot t+1: issued BEFORE the stores, so the
        //     counted wait at the next loop top retires it independently
        //     of the cross-XCD store-acks (in-order vmcnt).  Its flight
        //     overlaps the butterfly/tanh/store tail below. ---
        if (t + 1 < SEQ) {
            const u64* pn = (const u64*)
                (myring + (size_t)((t + 1) & (NSLOT - 1)) * HID + tid * 4);
            e0 = ld_agent(pn);
            e1 = ld_agent(pn + 1);
            asm volatile("" ::: "memory");   // pin issue order: loads first
        }

        // Paired butterfly: row (lane&3)'s full sum ends in lane l.
        a0 += __shfl_xor(a0, 1, 64);
        a1 += __shfl_xor(a1, 1, 64);
        a2 += __shfl_xor(a2, 1, 64);
        a3 += __shfl_xor(a3, 1, 64);
        float m01 = (lane & 1) ? a1 : a0;
        float m23 = (lane & 1) ? a3 : a2;
        m01 += __shfl_xor(m01, 2, 64);
        m23 += __shfl_xor(m23, 2, 64);
        float m = (lane & 2) ? m23 : m01;
        m += __shfl_xor(m, 4, 64);
        m += __shfl_xor(m, 8, 64);
        m += __shfl_xor(m, 16, 64);
        m += __shfl_xor(m, 32, 64);

        if (lane < 4) {
            float hn = fast_tanh(xav + m);
            const unsigned hu = __float_as_uint(hn);
            const int row = R0 + lane;
            const int s1 = (t + 1) & (NSLOT - 1);
            const int s5 = (t + 5) & (NSLOT - 1);
            // signals to ALL replicas first (consumer-critical), ...
#pragma unroll
            for (int r = 0; r < NREP; ++r)
                __hip_atomic_store(ring + ((size_t)r * NSLOT + s1) * HID + row,
                                   hu, __ATOMIC_RELAXED,
                                   __HIP_MEMORY_SCOPE_AGENT);
            // ... then poisons (needed 4 steps out), then plain H row.
#pragma unroll
            for (int r = 0; r < NREP; ++r)
                __hip_atomic_store(ring + ((size_t)r * NSLOT + s5) * HID + row,
                                   SENT, __ATOMIC_RELAXED,
                                   __HIP_MEMORY_SCOPE_AGENT);
            H[(size_t)(t + 1) * HID + row] = hn;   // epilogue GEMM input
        }
        // store IS the signal; unique addresses per slot -> race-free
    }
}

__global__ void copy_h(const float* __restrict__ src, float* __restrict__ dst)
{
    int i = blockIdx.x * blockDim.x + threadIdx.x;
    if (i < HID) dst[i] = src[i];
}

// ---------------------------------------------------------------------------
extern "C" void kernel_launch(void* const* d_in, const int* in_sizes, int n_in,
                              void* d_out, int out_size, void* d_ws, size_t ws_size,
                              hipStream_t stream)
{
    const int*   seq  = (const int*)  d_in[0];
    const float* emb  = (const float*)d_in[1];
    const float* wax  = (const float*)d_in[2];
    const float* waxb = (const float*)d_in[3];
    const float* waa  = (const float*)d_in[4];
    const float* wya  = (const float*)d_in[5];
    const float* wyab = (const float*)d_in[6];
    float* out = (float*)d_out;

    // ws layout: H[(SEQ+1)][HID] fp32 | P[NCH][HID] fp32 | ring[4][8][HID] u32
    float*    H    = (float*)d_ws;
    float*    P    = (float*)((char*)d_ws + (size_t)(SEQ + 1) * HID * sizeof(float));
    unsigned* ring = (unsigned*)(P + (size_t)NCH * HID);

    // Re-init every call: ring all-poison, then slot 0 of each replica = h0 = 0.
    (void)hipMemsetAsync(ring, 0xFF, (size_t)NREP * NSLOT * HID * sizeof(unsigned), stream);
    for (int r = 0; r < NREP; ++r)
        (void)hipMemsetAsync(ring + (size_t)r * NSLOT * HID, 0,
                             HID * sizeof(unsigned), stream);

    // P = emb @ wax^T + wax_b   (M=256, N=2048, K=1024)
    dim3 gA(NCH / 64, HID / 64);
    gemm_tn<<<gA, 256, 0, stream>>>(emb, wax, waxb, P, NCH, HID, EMB);

    // Sequential recurrence (persistent, flag-dataflow + ring poison sync).
    rnn_scan<<<SCAN_B, SCAN_T, 0, stream>>>(seq, waa, P, H, ring);

    // out = H[1..SEQ] @ wya^T + wya_b   (M=8192, N=256, K=2048)
    dim3 gC(SEQ / 64, NCH / 64);
    gemm_tn<<<gC, 256, 0, stream>>>(H + HID, wya, wyab, out, SEQ, NCH, HID);

    // h_final = H[SEQ] -> tail of d_out
    copy_h<<<(HID + 255) / 256, 256, 0, stream>>>(H + (size_t)SEQ * HID,
                                                  out + (size_t)SEQ * NCH);
}

// Round 9
// 15566.336 us; speedup vs baseline: 3.5295x; 1.0658x over previous
//
#include <hip/hip_runtime.h>
#include <stdint.h>

#define SEQ 8192
#define EMB 1024
#define HID 2048
#define NCH 256

#define SCAN_B 64                   // persistent blocks (co-resident, proven R1-R6)
#define SCAN_T 512                  // 8 waves/block
#define ROWS_PB (HID / SCAN_B)      // 32 rows per block (4 per wave)
#define SENT 0xFFFFFFFFu            // poison: tanh never produces this pattern
#define NREP 4                      // ring replicas (spread L3 line ownership)
#define NSLOT 8                     // ring slots (skew<=1 proven; margin 4)

typedef unsigned uint4v __attribute__((ext_vector_type(4)));

// ---------------------------------------------------------------------------
// Generic fp32 "TN" GEMM: C[m][n] = bias[n] + dot(X[m][:], W[n][:])
// ---------------------------------------------------------------------------
__global__ __launch_bounds__(256) void gemm_tn(const float* __restrict__ X,
                                               const float* __restrict__ W,
                                               const float* __restrict__ bias,
                                               float* __restrict__ C,
                                               int M, int N, int K)
{
    __shared__ float Xs[16][68];
    __shared__ float Ws[16][68];
    const int m0 = blockIdx.x * 64, n0 = blockIdx.y * 64;
    const int tid  = threadIdx.x;
    const int lrow = tid >> 2;
    const int kq   = (tid & 3) * 4;
    const int tx   = tid & 15, ty = tid >> 4;
    float acc[4][4] = {};
    const float* Xp = X + (size_t)(m0 + lrow) * K + kq;
    const float* Wp = W + (size_t)(n0 + lrow) * K + kq;

    for (int k0 = 0; k0 < K; k0 += 16) {
        float4 xv = *(const float4*)(Xp + k0);
        float4 wv = *(const float4*)(Wp + k0);
        __syncthreads();
        Xs[kq+0][lrow] = xv.x; Xs[kq+1][lrow] = xv.y;
        Xs[kq+2][lrow] = xv.z; Xs[kq+3][lrow] = xv.w;
        Ws[kq+0][lrow] = wv.x; Ws[kq+1][lrow] = wv.y;
        Ws[kq+2][lrow] = wv.z; Ws[kq+3][lrow] = wv.w;
        __syncthreads();
#pragma unroll
        for (int kk = 0; kk < 16; ++kk) {
            float4 av = *(const float4*)&Xs[kk][ty * 4];
            float4 bv = *(const float4*)&Ws[kk][tx * 4];
            float a[4] = {av.x, av.y, av.z, av.w};
            float b[4] = {bv.x, bv.y, bv.z, bv.w};
#pragma unroll
            for (int i = 0; i < 4; ++i)
#pragma unroll
                for (int j = 0; j < 4; ++j)
                    acc[i][j] += a[i] * b[j];
        }
    }
#pragma unroll
    for (int i = 0; i < 4; ++i) {
        const int m = m0 + ty * 4 + i;
#pragma unroll
        for (int j = 0; j < 4; ++j) {
            const int n = n0 + tx * 4 + j;
            C[(size_t)m * N + n] = acc[i][j] + bias[n];
        }
    }
}

// tanh(x) = 1 - 2/(exp2(2x*log2e)+1); ~1e-6 rel error, finite everywhere.
__device__ __forceinline__ float fast_tanh(float x)
{
    float e = __builtin_amdgcn_exp2f(x * 2.885390081777927f);
    return 1.0f - 2.0f * __builtin_amdgcn_rcpf(e + 1.0f);
}

// ---------------------------------------------------------------------------
// Persistent RNN scan (R6 compute, ring-replicated exchange) — proven-best
// protocol, restored verbatim after R7-R14 exploration:
//   Exchange lives in a tiny ring: ring[rep][slot][HID], rep=0..3, slot=t&7.
//   Producers (lanes 0-3 of each wave, 1 row each) write their h value to all
//   4 replicas of slot (t+1)&7 (relaxed AGENT stores -> coherence point),
//   plus one plain store to H[t+1] (read only by the epilogue GEMM), plus
//   re-poison slot (t+5)&7. Consumers poll replica (blockIdx&3) only ->
//   16 reader-blocks per 64B line instead of 64, and the whole polled set is
//   256 KB (L3-resident). Block skew is provably <=1 step (a block enters
//   step t+1 only after row t is complete, i.e. after ALL blocks finished
//   producing during step t), so slot reuse at distance 8 with poison at
//   distance 4 is race-free. Slot 0 of each replica is pre-zeroed (h0 = 0);
//   all other slots pre-poisoned.
//   Compute identical to R6 (proven): wave owns 4 rows, lane l covers cols
//   {256j+4l..+3}, 128 fp32 weights in regs, paired butterfly reduce.
//
//   Exploration record (R7-R14, all regressed or parity):
//     - flag-dataflow instead of barrier (R9): parity (+0.5%)
//     - 128x256 layout (R7): LDS bank conflicts 16-way, +22%
//     - asm in-flight prefetch (R8): UNSOUND (allocator reuses dest regs)
//     - post-store prefetch (R10): vmcnt in-order => store-ack drain, 4-10x
//     - store-wave split (R11): delays signal ~1400cy, +31%
//     - same-addr ping-pong poll (R12): MSHR coalesces, +10%
//     - direct ring->reg gather (R13): 8x coherent traffic, 5.6x
//     - pre-store early sample (R14): hit-rate ~1/4, +6%
//   Conclusion: per-step ~4500cy = ~900cy compute + ~3600cy cross-die
//   store->visibility + max-over-512-waves discovery at ~RTT sampling.
//   Protocol-independent fabric floor for 64-block 8KB all-gather x 8192.
// ---------------------------------------------------------------------------
__global__ __launch_bounds__(SCAN_T, 2) void rnn_scan(
    const int*  __restrict__ seq,
    const float* __restrict__ waa,
    const float* __restrict__ P,
    float* __restrict__ H,                 // (SEQ+1) x HID; plain (not polled)
    unsigned* __restrict__ ring)           // NREP x NSLOT x HID
{
    const int b    = blockIdx.x;
    const int tid  = threadIdx.x;
    const int wv   = tid >> 6;        // wave id 0..7
    const int lane = tid & 63;
    const int R0   = b * ROWS_PB + wv * 4;   // first of this wave's 4 rows
    const int rep  = b & (NREP - 1);

    __shared__ float hbuf[2][HID];    // 16 KB parity double-buffer

    // One-time weight load: w[i][4j+e] = waa[R0+i][256j+4*lane+e].
    float w0[32], w1[32], w2[32], w3[32];
#pragma unroll
    for (int j = 0; j < 8; ++j) {
        const float* base = waa + 256 * j + 4 * lane;
        float4 a = *(const float4*)(base + (size_t)(R0 + 0) * HID);
        float4 c = *(const float4*)(base + (size_t)(R0 + 1) * HID);
        float4 d = *(const float4*)(base + (size_t)(R0 + 2) * HID);
        float4 e = *(const float4*)(base + (size_t)(R0 + 3) * HID);
        w0[4*j+0]=a.x; w0[4*j+1]=a.y; w0[4*j+2]=a.z; w0[4*j+3]=a.w;
        w1[4*j+0]=c.x; w1[4*j+1]=c.y; w1[4*j+2]=c.z; w1[4*j+3]=c.w;
        w2[4*j+0]=d.x; w2[4*j+1]=d.y; w2[4*j+2]=d.z; w2[4*j+3]=d.w;
        w3[4*j+0]=e.x; w3[4*j+1]=e.y; w3[4*j+2]=e.z; w3[4*j+3]=e.w;
    }
#pragma unroll
    for (int k = 0; k < 32; ++k) {
        asm volatile("" : "+v"(w0[k])); asm volatile("" : "+v"(w1[k]));
        asm volatile("" : "+v"(w2[k])); asm volatile("" : "+v"(w3[k]));
    }

    unsigned* myring = ring + (size_t)rep * NSLOT * HID;

    for (int t = 0; t < SEQ; ++t) {
        // xa for this step (read-only, cached) -- overlaps the poll.
        const int ch = seq[t];
        float xav = 0.f;
        if (lane < 4) xav = P[(size_t)ch * HID + R0 + lane];

        // --- poll my 4 words of slot t&7 (agent-scope, R4-proven loop) ---
        {
            const unsigned long long* p8 = (const unsigned long long*)
                (myring + (size_t)(t & (NSLOT - 1)) * HID + tid * 4);
            unsigned long long a = __hip_atomic_load(p8 + 0, __ATOMIC_RELAXED,
                                                     __HIP_MEMORY_SCOPE_AGENT);
            unsigned long long c = __hip_atomic_load(p8 + 1, __ATOMIC_RELAXED,
                                                     __HIP_MEMORY_SCOPE_AGENT);
            while (((unsigned)a == SENT) || ((unsigned)(a >> 32) == SENT) ||
                   ((unsigned)c == SENT) || ((unsigned)(c >> 32) == SENT)) {
                __builtin_amdgcn_s_sleep(1);
                a = __hip_atomic_load(p8 + 0, __ATOMIC_RELAXED,
                                      __HIP_MEMORY_SCOPE_AGENT);
                c = __hip_atomic_load(p8 + 1, __ATOMIC_RELAXED,
                                      __HIP_MEMORY_SCOPE_AGENT);
            }
            uint4v v;
            v.x = (unsigned)a; v.y = (unsigned)(a >> 32);
            v.z = (unsigned)c; v.w = (unsigned)(c >> 32);
            *(uint4v*)&hbuf[t & 1][tid * 4] = v;
        }
        __syncthreads();

        // --- 8 conflict-free b128 reads, 128 FMAs over 4 rows (R6) ---
        float a0 = 0.f, a1 = 0.f, a2 = 0.f, a3 = 0.f;
        const float* hb = &hbuf[t & 1][4 * lane];
#pragma unroll
        for (int j = 0; j < 8; ++j) {
            float4 hv = *(const float4*)(hb + 256 * j);
            a0 += w0[4*j+0]*hv.x + w0[4*j+1]*hv.y + w0[4*j+2]*hv.z + w0[4*j+3]*hv.w;
            a1 += w1[4*j+0]*hv.x + w1[4*j+1]*hv.y + w1[4*j+2]*hv.z + w1[4*j+3]*hv.w;
            a2 += w2[4*j+0]*hv.x + w2[4*j+1]*hv.y + w2[4*j+2]*hv.z + w2[4*j+3]*hv.w;
            a3 += w3[4*j+0]*hv.x + w3[4*j+1]*hv.y + w3[4*j+2]*hv.z + w3[4*j+3]*hv.w;
        }
        // Paired butterfly: row (lane&3)'s full sum ends in lane l.
        a0 += __shfl_xor(a0, 1, 64);
        a1 += __shfl_xor(a1, 1, 64);
        a2 += __shfl_xor(a2, 1, 64);
        a3 += __shfl_xor(a3, 1, 64);
        float m01 = (lane & 1) ? a1 : a0;
        float m23 = (lane & 1) ? a3 : a2;
        m01 += __shfl_xor(m01, 2, 64);
        m23 += __shfl_xor(m23, 2, 64);
        float m = (lane & 2) ? m23 : m01;
        m += __shfl_xor(m, 4, 64);
        m += __shfl_xor(m, 8, 64);
        m += __shfl_xor(m, 16, 64);
        m += __shfl_xor(m, 32, 64);

        if (lane < 4) {
            float hn = fast_tanh(xav + m);
            const unsigned hu = __float_as_uint(hn);
            const int row = R0 + lane;
            const int s1 = (t + 1) & (NSLOT - 1);
            const int s5 = (t + 5) & (NSLOT - 1);
#pragma unroll
            for (int r = 0; r < NREP; ++r) {
                unsigned* rb = ring + (size_t)r * NSLOT * HID;
                __hip_atomic_store(rb + (size_t)s1 * HID + row, hu,
                                   __ATOMIC_RELAXED, __HIP_MEMORY_SCOPE_AGENT);
                __hip_atomic_store(rb + (size_t)s5 * HID + row, SENT,
                                   __ATOMIC_RELAXED, __HIP_MEMORY_SCOPE_AGENT);
            }
            H[(size_t)(t + 1) * HID + row] = hn;   // epilogue GEMM input
        }
        // store IS the signal; unique addresses per slot -> race-free
    }
}

__global__ void copy_h(const float* __restrict__ src, float* __restrict__ dst)
{
    int i = blockIdx.x * blockDim.x + threadIdx.x;
    if (i < HID) dst[i] = src[i];
}

// ---------------------------------------------------------------------------
extern "C" void kernel_launch(void* const* d_in, const int* in_sizes, int n_in,
                              void* d_out, int out_size, void* d_ws, size_t ws_size,
                              hipStream_t stream)
{
    const int*   seq  = (const int*)  d_in[0];
    const float* emb  = (const float*)d_in[1];
    const float* wax  = (const float*)d_in[2];
    const float* waxb = (const float*)d_in[3];
    const float* waa  = (const float*)d_in[4];
    const float* wya  = (const float*)d_in[5];
    const float* wyab = (const float*)d_in[6];
    float* out = (float*)d_out;

    // ws layout: H[(SEQ+1)][HID] fp32 | P[NCH][HID] fp32 | ring[4][8][HID] u32
    float*    H    = (float*)d_ws;
    float*    P    = (float*)((char*)d_ws + (size_t)(SEQ + 1) * HID * sizeof(float));
    unsigned* ring = (unsigned*)(P + (size_t)NCH * HID);

    // Re-init every call: ring all-poison, then slot 0 of each replica = h0 = 0.
    (void)hipMemsetAsync(ring, 0xFF, (size_t)NREP * NSLOT * HID * sizeof(unsigned), stream);
    for (int r = 0; r < NREP; ++r)
        (void)hipMemsetAsync(ring + (size_t)r * NSLOT * HID, 0,
                             HID * sizeof(unsigned), stream);

    // P = emb @ wax^T + wax_b   (M=256, N=2048, K=1024)
    dim3 gA(NCH / 64, HID / 64);
    gemm_tn<<<gA, 256, 0, stream>>>(emb, wax, waxb, P, NCH, HID, EMB);

    // Sequential recurrence (persistent, ring-replicated poison sync).
    rnn_scan<<<SCAN_B, SCAN_T, 0, stream>>>(seq, waa, P, H, ring);

    // out = H[1..SEQ] @ wya^T + wya_b   (M=8192, N=256, K=2048)
    dim3 gC(SEQ / 64, NCH / 64);
    gemm_tn<<<gC, 256, 0, stream>>>(H + HID, wya, wyab, out, SEQ, NCH, HID);

    // h_final = H[SEQ] -> tail of d_out
    copy_h<<<(HID + 255) / 256, 256, 0, stream>>>(H + (size_t)SEQ * HID,
                                                  out + (size_t)SEQ * NCH);
}